// Round 17
// baseline (95.392 us; speedup 1.0000x reference)
//
#include <hip/hip_runtime.h>
#include <hip/hip_cooperative_groups.h>
#include <math.h>

#define N_AA 21
#define NATOM 15
#define DF 128
#define H1DIM 256
#define OFF_COORD 128
#define OFF_DIH 1073
#define OFF_CHAIN 1112
#define T 16        // rows per block (one 16-row type-pure tile)
#define FT 32       // fallback rows per block
#define DIH0 46     // (fallback only)
#define HS1 264     // h1/h3 LDS row stride (ushort)
#define HS2 136     // h2 LDS row stride (ushort)
#define FS 104      // feature LDS row stride (ushort); 96 cols used
#define NFRAG_CH 16 // frag-packed chunks for W2|W3|W4
#define INVALID_IDX 0xFFFFFFFFu
#define SSTRIDE 260 // prep LDS stage stride (fp32)

// prep role boundaries (blocks)
#define PR_TAB 31
#define PR_WF 16
#define PR_WL 63

typedef __attribute__((ext_vector_type(8))) short s16x8;
typedef __attribute__((ext_vector_type(4))) float f32x4;

__constant__ float c_freq[6] = {1.0f, 2.0f, 3.0f, 1.0f, 0.5f, 1.0f / 3.0f};

#define FMA4(A, S, W)            \
  A.x = fmaf((S), (W).x, A.x);   \
  A.y = fmaf((S), (W).y, A.y);   \
  A.z = fmaf((S), (W).z, A.z);   \
  A.w = fmaf((S), (W).w, A.w);

__device__ inline float bf2f(unsigned short u) {
  union { unsigned int i; float f; } x;
  x.i = (unsigned)u << 16;
  return x.f;
}
__device__ inline unsigned short f2bf(float f) {  // RNE
  unsigned int x = __float_as_uint(f);
  unsigned int r = (x + 0x7fffu + ((x >> 16) & 1u)) >> 16;
  return (unsigned short)r;
}

// ================= shared role bodies (device inline) =================
__device__ inline void prep_role(
    int b, int tid, float* s_stage, int* s_h,
    const float* __restrict__ aa_emb, const float* __restrict__ chain_emb,
    const float* __restrict__ W1, const float* __restrict__ b1,
    const float* __restrict__ W2, const float* __restrict__ W3,
    const float* __restrict__ W4, const int* __restrict__ seq, int n,
    float* __restrict__ tabAA, float* __restrict__ tabCH,
    unsigned short* __restrict__ wf_hi, unsigned short* __restrict__ wf_lo,
    unsigned short* __restrict__ wl1, int* __restrict__ part) {
  if (b < PR_TAB) {
    const int i = tid;
    if (b < N_AA) {
      const float* e = aa_emb + b * DF;
      float acc = 0.f;
#pragma unroll 8
      for (int k = 0; k < DF; ++k) acc = fmaf(e[k], W1[k * H1DIM + i], acc);
      tabAA[b * H1DIM + i] = acc;
    } else {
      const int c = b - N_AA;
      const float* e = chain_emb + c * DF;
      float acc = b1[i];
#pragma unroll 8
      for (int k = 0; k < DF; ++k)
        acc = fmaf(e[k], W1[(OFF_CHAIN + k) * H1DIM + i], acc);
      tabCH[c * H1DIM + i] = acc;
    }
  } else if (b < PR_TAB + PR_WF) {
    const int cgb = b - PR_TAB;
    const float* W;
    int kbase;
    if (cgb < 8) { W = W2; kbase = cgb * 32; }
    else if (cgb < 12) { W = W3; kbase = (cgb - 8) * 32; }
    else { W = W4; kbase = (cgb - 12) * 32; }
    for (int idx = tid; idx < 32 * 128; idx += 256) {
      const int k = idx >> 7, col = idx & 127;
      s_stage[k * SSTRIDE + col] = W[(kbase + k) * DF + col];
    }
    __syncthreads();
    for (int e = tid; e < 8 * 512; e += 256) {
      const int rem = e & 511;
      const int nt = e >> 9;
      const int l = rem >> 3, jj = rem & 7;
      const int col = nt * 16 + (l & 15);
      const int k = (l >> 4) * 8 + jj;
      const float v = s_stage[k * SSTRIDE + col];
      const unsigned short h = f2bf(v);
      wf_hi[(size_t)cgb * 4096 + e] = h;
      wf_lo[(size_t)cgb * 4096 + e] = f2bf(v - bf2f(h));
    }
  } else if (b < PR_TAB + PR_WF + PR_WL) {
    const int b2 = b - PR_TAB - PR_WF;  // 0..62
    const int t = b2 / 3, c = b2 % 3;
    for (int idx = tid; idx < 32 * 256; idx += 256) {
      const int kp = idx >> 8, col = idx & 255;
      const int k = c * 32 + kp;
      float v = 0.f;
      if (k < 45) v = W1[(OFF_COORD + t * 45 + k) * H1DIM + col];
      else if (k < 84) v = W1[(OFF_DIH + (k - 45)) * H1DIM + col];
      s_stage[kp * SSTRIDE + col] = v;
    }
    __syncthreads();
    for (int e = tid; e < 16 * 512; e += 256) {
      const int rem = e & 511;
      const int nt = e >> 9;
      const int l = rem >> 3, j = rem & 7;
      const int col = nt * 16 + (l & 15);
      const int kp = (l >> 4) * 8 + j;
      wl1[(size_t)b2 * 8192 + e] = f2bf(s_stage[kp * SSTRIDE + col]);
    }
  } else {
    const int hb = b - PR_TAB - PR_WF - PR_WL;
    if (tid < N_AA) s_h[tid] = 0;
    __syncthreads();
    const int i = hb * 256 + tid;
    if (i < n) atomicAdd(&s_h[seq[i]], 1);
    __syncthreads();
    if (tid < N_AA) part[hb * N_AA + tid] = s_h[tid];
  }
}

__device__ inline void scatter_role(
    int b, int tid, int (*ps_tot)[9], int (*ps_base)[9], int* s_tot,
    int* s_base, int* s_off, int* h, const int* __restrict__ seq, int n,
    int cap, int nblkH, const int* __restrict__ part, int* __restrict__ totals,
    unsigned int* __restrict__ perm) {
  const int myhb = b - N_AA - 1;
  const int segLen = (nblkH + 7) >> 3;
  if (tid < N_AA * 8) {
    const int t = tid >> 3, seg = tid & 7;
    int tot = 0, bas = 0;
    for (int j = 0; j < segLen; ++j) {
      const int hb = seg * segLen + j;
      if (hb < nblkH) {
        const int v = part[hb * N_AA + t];
        tot += v;
        if (hb < myhb) bas += v;
      }
    }
    ps_tot[t][seg] = tot;
    ps_base[t][seg] = bas;
  }
  __syncthreads();
  if (tid < N_AA) {
    int tot = 0, bas = 0;
#pragma unroll
    for (int s = 0; s < 8; ++s) { tot += ps_tot[tid][s]; bas += ps_base[tid][s]; }
    s_tot[tid] = tot;
    s_base[tid] = bas;
  }
  __syncthreads();
  if (tid == 0) {
    int acc = 0;
    s_off[0] = 0;
    for (int tt = 0; tt < N_AA; ++tt) {
      acc += (s_tot[tt] + 15) & ~15;
      s_off[tt + 1] = acc;
    }
  }
  __syncthreads();
  if (b < N_AA) {
    const int padstart = s_off[b] + s_tot[b];
    const int padcnt = s_off[b + 1] - padstart;
    if (tid < padcnt) perm[padstart + tid] = INVALID_IDX;
  } else if (b == N_AA) {
    for (int i = s_off[N_AA] + tid; i < cap; i += 256) perm[i] = INVALID_IDX;
    if (tid < N_AA) totals[tid] = s_tot[tid];
  } else {
    if (tid < N_AA) h[tid] = 0;
    __syncthreads();
    const int i = myhb * 256 + tid;
    if (i < n) {
      const int tt = seq[i];
      const int slot = atomicAdd(&h[tt], 1);
      perm[s_off[tt] + s_base[tt] + slot] = (unsigned int)i;
    }
  }
}

// ---------------- fused cooperative prep+scatter ----------------
__global__ __launch_bounds__(256) void prep_scatter(
    const float* aa_emb, const float* chain_emb, const float* W1,
    const float* b1, const float* W2, const float* W3, const float* W4,
    const int* seq, int n, float* tabAA, float* tabCH,
    unsigned short* wf_hi, unsigned short* wf_lo, unsigned short* wl1,
    int* part, int cap, int nblkH, int* totals, unsigned int* perm) {
  __shared__ float s_stage[32 * SSTRIDE];
  __shared__ int s_h[N_AA];
  __shared__ int ps_tot[N_AA][9];
  __shared__ int ps_base[N_AA][9];
  __shared__ int s_tot[N_AA];
  __shared__ int s_base[N_AA];
  __shared__ int s_off[N_AA + 1];
  const int b = blockIdx.x;
  const int tid = threadIdx.x;
  prep_role(b, tid, s_stage, s_h, aa_emb, chain_emb, W1, b1, W2, W3, W4, seq,
            n, tabAA, tabCH, wf_hi, wf_lo, wl1, part);
  cooperative_groups::this_grid().sync();
  if (b < nblkH + N_AA + 1)
    scatter_role(b, tid, ps_tot, ps_base, s_tot, s_base, s_off, s_h, seq, n,
                 cap, nblkH, part, totals, perm);
}

// ---------------- separate-kernel fallbacks (r16-proven) ----------------
__global__ __launch_bounds__(256) void prep_all(
    const float* __restrict__ aa_emb, const float* __restrict__ chain_emb,
    const float* __restrict__ W1, const float* __restrict__ b1,
    const float* __restrict__ W2, const float* __restrict__ W3,
    const float* __restrict__ W4, const int* __restrict__ seq, int n,
    float* __restrict__ tabAA, float* __restrict__ tabCH,
    unsigned short* __restrict__ wf_hi, unsigned short* __restrict__ wf_lo,
    unsigned short* __restrict__ wl1, int* __restrict__ part) {
  __shared__ float s_stage[32 * SSTRIDE];
  __shared__ int s_h[N_AA];
  prep_role(blockIdx.x, threadIdx.x, s_stage, s_h, aa_emb, chain_emb, W1, b1,
            W2, W3, W4, seq, n, tabAA, tabCH, wf_hi, wf_lo, wl1, part);
}

__global__ __launch_bounds__(256) void scatter_pad(
    const int* __restrict__ seq, int n, int cap, int nblkH,
    const int* __restrict__ part, int* __restrict__ totals,
    unsigned int* __restrict__ perm) {
  __shared__ int ps_tot[N_AA][9];
  __shared__ int ps_base[N_AA][9];
  __shared__ int s_tot[N_AA];
  __shared__ int s_base[N_AA];
  __shared__ int s_off[N_AA + 1];
  __shared__ int h[N_AA];
  scatter_role(blockIdx.x, threadIdx.x, ps_tot, ps_base, s_tot, s_base, s_off,
               h, seq, n, cap, nblkH, part, totals, perm);
}

// ---------------- main kernel: hi-only activations + cross-barrier prefetch ----------------
__global__ __launch_bounds__(256, 8) void residue_embed_sorted(
    const float* __restrict__ xyz, const float* __restrict__ orient,
    const float* __restrict__ dihedrals, const int* __restrict__ chain_idx,
    const float* __restrict__ amask, const float* __restrict__ b2,
    const float* __restrict__ b3, const float* __restrict__ b4,
    const float* __restrict__ tabAA, const float* __restrict__ tabCH,
    const unsigned short* __restrict__ wl1, const unsigned short* __restrict__ wf_hi,
    const unsigned short* __restrict__ wf_lo, const int* __restrict__ totals,
    const unsigned int* __restrict__ perm, float* __restrict__ out) {
  __shared__ unsigned short s_h1hi[T][HS1];  // h1 hi; later h3 hi (cols 0..127)
  __shared__ __align__(16) char s_u[T * HS2 * 2];  // feat-hi [16][FS] | h2-hi [16][HS2]
  __shared__ unsigned int s_g[T];
  __shared__ int s_c[T];
  __shared__ int s_off[N_AA + 1];
  __shared__ int s_cnt[N_AA];

  unsigned short (*s_fh)[FS] = (unsigned short(*)[FS])s_u;
  unsigned short (*s_h2hi)[HS2] = (unsigned short(*)[HS2])s_u;

  const int tid = threadIdx.x;
  const int base = blockIdx.x * T;

  if (tid < T) {
    const unsigned int g = perm[base + tid];
    s_g[tid] = g;
    s_c[tid] = (g != INVALID_IDX) ? chain_idx[g] : 0;
  }
  if (tid >= 32 && tid < 32 + N_AA) s_cnt[tid - 32] = totals[tid - 32];
  __syncthreads();
  if (tid == 0) {
    int acc = 0;
    s_off[0] = 0;
    for (int t2 = 0; t2 < N_AA; ++t2) {
      acc += (s_cnt[t2] + 15) & ~15;
      s_off[t2 + 1] = acc;
    }
  }

  // ---- phase 0: gather via s_g; features -> bf16 LDS (hi only) ----
  for (int idx = tid; idx < T * 45; idx += 256) {
    const int r = idx / 45, k = idx % 45;
    const int a = k / 3, i = k % 3;
    const unsigned int g = s_g[r];
    float v = 0.f;
    if (g != INVALID_IDX) {
      const float* X = xyz + (size_t)g * 45;
      const float* R = orient + (size_t)g * 9;
      const float m = amask[(size_t)g * NATOM + a];
#pragma unroll
      for (int j = 0; j < 3; ++j)
        v = fmaf(R[j * 3 + i], X[a * 3 + j] - X[3 + j], v);  // CA = atom 1
      v *= m;
    }
    s_fh[r][k] = f2bf(v);
  }
  for (int idx = tid; idx < T * 39; idx += 256) {
    const int r = idx / 39, kk = idx % 39;
    const int d = kk / 13, m = kk % 13;
    const unsigned int g = s_g[r];
    float v = 0.f;
    if (g != INVALID_IDX) {
      const float x = dihedrals[(size_t)g * 3 + d];
      if (m == 0) v = x;
      else if (m <= 6) v = sinf(c_freq[m - 1] * x);
      else v = cosf(c_freq[m - 7] * x);
    }
    s_fh[r][45 + kk] = f2bf(v);
  }
  for (int idx = tid; idx < T * 12; idx += 256) {  // zero pad k 84..95
    const int r = idx / 12, k = 84 + idx % 12;
    s_fh[r][k] = 0;
  }
  __syncthreads();  // features + s_off visible

  // ---- MFMA tiling constants (4 waves: wave = col group) ----
  const int l = tid & 63;
  const int nc = tid >> 6;           // wave 0..3
  const int nc0 = nc * 32;           // layers 2-4 col base (DF=128)
  const int ar = l & 15;             // A row (residue)
  const int kb = (l >> 4) * 8;
  const int drow = (l >> 4) * 4;
  const size_t fbase = (size_t)(2 * nc) * 512 + (size_t)l * 8;

  // tile type (whole block is one type-pure 16-tile)
  int ty = 0;
#pragma unroll
  for (int t2 = 1; t2 < N_AA; ++t2)
    if (base >= s_off[t2]) ty = t2;

  // ---- layer 1: h1 = relu(feat96 @ W1type + tabAA[ty] + tabCH[chain]) ----
  {
    f32x4 acc[4] = {{0.f, 0.f, 0.f, 0.f}, {0.f, 0.f, 0.f, 0.f},
                    {0.f, 0.f, 0.f, 0.f}, {0.f, 0.f, 0.f, 0.f}};
    s16x8 ah[3];
#pragma unroll
    for (int c = 0; c < 3; ++c)
      ah[c] = *(const s16x8*)(&s_fh[ar][c * 32 + kb]);
    const unsigned short* pB = wl1 + ((size_t)ty * 48 + 4 * nc) * 512 + (size_t)l * 8;
#pragma unroll
    for (int c = 0; c < 3; ++c) {
#pragma unroll
      for (int nt2 = 0; nt2 < 4; ++nt2) {
        const s16x8 bb = *(const s16x8*)(pB + ((size_t)c * 16 + nt2) * 512);
        acc[nt2] = __builtin_amdgcn_mfma_f32_16x16x32_bf16(ah[c], bb, acc[nt2], 0, 0, 0);
      }
    }
    // (h1-publish barrier below also fences feature reads vs h2 overwrite)
#pragma unroll
    for (int nt2 = 0; nt2 < 4; ++nt2) {
      const int col0 = nc * 64 + nt2 * 16 + (l & 15);
      const float ta = tabAA[ty * H1DIM + col0];
#pragma unroll
      for (int reg = 0; reg < 4; ++reg) {
        const int row = drow + reg;
        float v = acc[nt2][reg] + ta + tabCH[s_c[row] * H1DIM + col0];
        v = fmaxf(v, 0.f);
        s_h1hi[row][col0] = f2bf(v);
      }
    }
  }

// Prefetch a layer's chunk-0 B-fragments into registers BEFORE the barrier
// that publishes its activation input (global loads, independent of LDS).
#define PRELOAD_FRAGS(P, CG0)                                                    \
  s16x8 P##b0h, P##b1h, P##b0l, P##b1l;                                          \
  {                                                                              \
    const unsigned short* ph_ = wf_hi + (size_t)(CG0)*4096 + fbase;              \
    const unsigned short* pl_ = wf_lo + (size_t)(CG0)*4096 + fbase;              \
    P##b0h = *(const s16x8*)(ph_);                                               \
    P##b1h = *(const s16x8*)(ph_ + 512);                                         \
    P##b0l = *(const s16x8*)(pl_);                                               \
    P##b1l = *(const s16x8*)(pl_ + 512);                                         \
  }

#define MFMA_LAYER_P(NCHUNK, CG0, P, SRCH, SSTR, BPTR, EPI)                      \
  do {                                                                           \
    f32x4 acc0 = {0.f, 0.f, 0.f, 0.f}, acc1 = {0.f, 0.f, 0.f, 0.f};             \
    const unsigned short* ph = wf_hi + (size_t)(CG0)*4096 + fbase;               \
    const unsigned short* pl = wf_lo + (size_t)(CG0)*4096 + fbase;               \
    {                                                                            \
      const s16x8 ah = *(const s16x8*)((SRCH) + ar * (SSTR) + kb);               \
      acc0 = __builtin_amdgcn_mfma_f32_16x16x32_bf16(ah, P##b0h, acc0, 0, 0, 0); \
      acc1 = __builtin_amdgcn_mfma_f32_16x16x32_bf16(ah, P##b1h, acc1, 0, 0, 0); \
      acc0 = __builtin_amdgcn_mfma_f32_16x16x32_bf16(ah, P##b0l, acc0, 0, 0, 0); \
      acc1 = __builtin_amdgcn_mfma_f32_16x16x32_bf16(ah, P##b1l, acc1, 0, 0, 0); \
    }                                                                            \
    _Pragma("unroll 2")                                                          \
    for (int c = 1; c < (NCHUNK); ++c) {                                         \
      const s16x8 b0h = *(const s16x8*)(ph + (size_t)c * 4096);                  \
      const s16x8 b1h = *(const s16x8*)(ph + (size_t)c * 4096 + 512);            \
      const s16x8 b0l = *(const s16x8*)(pl + (size_t)c * 4096);                  \
      const s16x8 b1l = *(const s16x8*)(pl + (size_t)c * 4096 + 512);            \
      const int ko = c * 32 + kb;                                                \
      const s16x8 ah = *(const s16x8*)((SRCH) + ar * (SSTR) + ko);               \
      acc0 = __builtin_amdgcn_mfma_f32_16x16x32_bf16(ah, b0h, acc0, 0, 0, 0);    \
      acc1 = __builtin_amdgcn_mfma_f32_16x16x32_bf16(ah, b1h, acc1, 0, 0, 0);    \
      acc0 = __builtin_amdgcn_mfma_f32_16x16x32_bf16(ah, b0l, acc0, 0, 0, 0);    \
      acc1 = __builtin_amdgcn_mfma_f32_16x16x32_bf16(ah, b1l, acc1, 0, 0, 0);    \
    }                                                                            \
    const float bias0 = (BPTR)[nc0 + (l & 15)];                                  \
    const float bias1 = (BPTR)[nc0 + 16 + (l & 15)];                             \
    EPI                                                                          \
  } while (0)

#define EPI_HIDDEN(DH, DSTR)                                                     \
  {                                                                              \
    _Pragma("unroll")                                                            \
    for (int reg = 0; reg < 4; ++reg) {                                          \
      const int row = drow + reg;                                                \
      float v0 = fmaxf(acc0[reg] + bias0, 0.f);                                  \
      float v1 = fmaxf(acc1[reg] + bias1, 0.f);                                  \
      (DH)[row * (DSTR) + nc0 + (l & 15)] = f2bf(v0);                            \
      (DH)[row * (DSTR) + nc0 + 16 + (l & 15)] = f2bf(v1);                       \
    }                                                                            \
  }

  PRELOAD_FRAGS(p2, 0);
  __syncthreads();  // h1 visible

  // ---- layer 2: K=256 (h2 overwrites feature region of s_u) ----
  MFMA_LAYER_P(8, 0, p2, &s_h1hi[0][0], HS1, b2, EPI_HIDDEN(&s_h2hi[0][0], HS2));
  PRELOAD_FRAGS(p3, 8);
  __syncthreads();  // h2 visible

  // ---- layer 3: K=128 -> overwrite s_h1 ----
  MFMA_LAYER_P(4, 8, p3, &s_h2hi[0][0], HS2, b3, EPI_HIDDEN(&s_h1hi[0][0], HS1));
  PRELOAD_FRAGS(p4, 12);
  __syncthreads();  // h3 visible

  // ---- layer 4: K=128, scatter-store via perm ----
  MFMA_LAYER_P(4, 12, p4, &s_h1hi[0][0], HS1, b4, {
    _Pragma("unroll")
    for (int reg = 0; reg < 4; ++reg) {
      const unsigned int g = s_g[drow + reg];
      if (g != INVALID_IDX) {
        out[(size_t)g * DF + nc0 + (l & 15)] = acc0[reg] + bias0;
        out[(size_t)g * DF + nc0 + 16 + (l & 15)] = acc1[reg] + bias1;
      }
    }
  });
}

// ---------------- fp32 fallback path kernels ----------------
__global__ __launch_bounds__(256) void precompute_tables(
    const float* __restrict__ aa_emb, const float* __restrict__ chain_emb,
    const float* __restrict__ W1, const float* __restrict__ b1,
    float* __restrict__ tabAA, float* __restrict__ tabCH) {
  const int i = threadIdx.x;
  const int b = blockIdx.x;
  if (b < N_AA) {
    const float* e = aa_emb + b * DF;
    float acc = 0.f;
#pragma unroll 8
    for (int k = 0; k < DF; ++k) acc = fmaf(e[k], W1[k * H1DIM + i], acc);
    tabAA[b * H1DIM + i] = acc;
  } else {
    const int c = b - N_AA;
    const float* e = chain_emb + c * DF;
    float acc = b1[i];
#pragma unroll 8
    for (int k = 0; k < DF; ++k)
      acc = fmaf(e[k], W1[(OFF_CHAIN + k) * H1DIM + i], acc);
    tabCH[c * H1DIM + i] = acc;
  }
}

__global__ __launch_bounds__(512, 4) void residue_embed_fallback(
    const int* __restrict__ seq_idx, const float* __restrict__ xyz,
    const float* __restrict__ orient, const float* __restrict__ dihedrals,
    const int* __restrict__ chain_idx, const float* __restrict__ amask,
    const float* __restrict__ W1, const float* __restrict__ W2,
    const float* __restrict__ b2, const float* __restrict__ W3,
    const float* __restrict__ b3, const float* __restrict__ W4,
    const float* __restrict__ b4, const float* __restrict__ tabAA,
    const float* __restrict__ tabCH, float* __restrict__ out) {
  __shared__ float s_h1[FT][260];
  __shared__ float s_buf2[FT][132];
  __shared__ float s_w[32 * DF];
  __shared__ int s_t[FT];
  __shared__ int s_c[FT];

  const int tid = threadIdx.x;
  const int base = blockIdx.x * FT;

  if (tid < FT) {
    s_t[tid] = seq_idx[base + tid];
    s_c[tid] = chain_idx[base + tid];
  }
  for (int idx = tid; idx < FT * 45; idx += 512) {
    const int r = idx / 45, k = idx % 45;
    const int a = k / 3, i = k % 3;
    const int g = base + r;
    const float* X = xyz + g * 45;
    const float* R = orient + g * 9;
    const float m = amask[g * NATOM + a];
    float v = 0.f;
#pragma unroll
    for (int j = 0; j < 3; ++j)
      v = fmaf(R[j * 3 + i], X[a * 3 + j] - X[3 + j], v);
    s_buf2[r][k] = v * m;
  }
  for (int idx = tid; idx < FT * 39; idx += 512) {
    const int r = idx / 39, k = idx % 39;
    const int d = k / 13, m = k % 13;
    const float x = dihedrals[(base + r) * 3 + d];
    float v;
    if (m == 0) v = x;
    else if (m <= 6) v = sinf(c_freq[m - 1] * x);
    else v = cosf(c_freq[m - 7] * x);
    s_buf2[r][DIH0 + k] = v;
  }
  __syncthreads();
  {
    const int i0 = (tid & 63) * 4;
    const int r0 = (tid >> 6) * 4;
    float4 acc[4];
#pragma unroll
    for (int rr = 0; rr < 4; ++rr) {
      const int t = s_t[r0 + rr], c = s_c[r0 + rr];
      const float4 a = *(const float4*)(tabAA + t * H1DIM + i0);
      const float4 b = *(const float4*)(tabCH + c * H1DIM + i0);
      acc[rr].x = a.x + b.x; acc[rr].y = a.y + b.y;
      acc[rr].z = a.z + b.z; acc[rr].w = a.w + b.w;
    }
#pragma unroll 3
    for (int k = 0; k < 39; ++k) {
      const float4 wv = *(const float4*)(W1 + (OFF_DIH + k) * H1DIM + i0);
#pragma unroll
      for (int rr = 0; rr < 4; ++rr) {
        FMA4(acc[rr], s_buf2[r0 + rr][DIH0 + k], wv);
      }
    }
    const float* wp[4];
#pragma unroll
    for (int rr = 0; rr < 4; ++rr)
      wp[rr] = W1 + (OFF_COORD + s_t[r0 + rr] * 45) * H1DIM + i0;
    for (int k = 0; k < 45; ++k) {
#pragma unroll
      for (int rr = 0; rr < 4; ++rr) {
        const float4 wv = *(const float4*)(wp[rr] + k * H1DIM);
        FMA4(acc[rr], s_buf2[r0 + rr][k], wv);
      }
    }
#pragma unroll
    for (int rr = 0; rr < 4; ++rr) {
      float4 v;
      v.x = fmaxf(acc[rr].x, 0.f); v.y = fmaxf(acc[rr].y, 0.f);
      v.z = fmaxf(acc[rr].z, 0.f); v.w = fmaxf(acc[rr].w, 0.f);
      *(float4*)(&s_h1[r0 + rr][i0]) = v;
    }
  }
  const int j0 = (tid & 31) * 4;
  const int r2 = (tid >> 5) * 2;
#define FB_LAYER(NCH, WSRC, SRC, BPTR, STORE)                               \
  do {                                                                      \
    const float4 bb = *(const float4*)((BPTR) + j0);                        \
    float4 acc0 = bb, acc1 = bb;                                            \
    for (int c = 0; c < (NCH); ++c) {                                       \
      __syncthreads();                                                      \
      {                                                                     \
        const float* src = (WSRC) + c * 32 * DF;                            \
        const int idx = tid * 8;                                            \
        *(float4*)(&s_w[idx]) = *(const float4*)(src + idx);                \
        *(float4*)(&s_w[idx + 4]) = *(const float4*)(src + idx + 4);        \
      }                                                                     \
      __syncthreads();                                                      \
      const int kb2 = c * 32;                                               \
      _Pragma("unroll")                                                     \
      for (int kk = 0; kk < 32; kk += 4) {                                  \
        const float4 a0 = *(const float4*)(&(SRC)[r2][kb2 + kk]);           \
        const float4 a1 = *(const float4*)(&(SRC)[r2 + 1][kb2 + kk]);       \
        const float4 w0 = *(const float4*)(&s_w[(kk + 0) * DF + j0]);       \
        const float4 w1 = *(const float4*)(&s_w[(kk + 1) * DF + j0]);       \
        const float4 w2 = *(const float4*)(&s_w[(kk + 2) * DF + j0]);       \
        const float4 w3 = *(const float4*)(&s_w[(kk + 3) * DF + j0]);       \
        FMA4(acc0, a0.x, w0); FMA4(acc1, a1.x, w0);                         \
        FMA4(acc0, a0.y, w1); FMA4(acc1, a1.y, w1);                         \
        FMA4(acc0, a0.z, w2); FMA4(acc1, a1.z, w2);                         \
        FMA4(acc0, a0.w, w3); FMA4(acc1, a1.w, w3);                         \
      }                                                                     \
    }                                                                       \
    STORE                                                                   \
  } while (0)
#define RELU_STORE(DST)                                                     \
  {                                                                         \
    float4 v0, v1;                                                          \
    v0.x = fmaxf(acc0.x, 0.f); v0.y = fmaxf(acc0.y, 0.f);                   \
    v0.z = fmaxf(acc0.z, 0.f); v0.w = fmaxf(acc0.w, 0.f);                   \
    v1.x = fmaxf(acc1.x, 0.f); v1.y = fmaxf(acc1.y, 0.f);                   \
    v1.z = fmaxf(acc1.z, 0.f); v1.w = fmaxf(acc1.w, 0.f);                   \
    *(float4*)(&(DST)[r2][j0]) = v0;                                        \
    *(float4*)(&(DST)[r2 + 1][j0]) = v1;                                    \
  }
  FB_LAYER(8, W2, s_h1, b2, RELU_STORE(s_buf2));
  FB_LAYER(4, W3, s_buf2, b3, RELU_STORE(s_h1));
  FB_LAYER(4, W4, s_h1, b4, {
    *(float4*)(out + (size_t)(base + r2) * DF + j0) = acc0;
    *(float4*)(out + (size_t)(base + r2 + 1) * DF + j0) = acc1;
  });
}

extern "C" void kernel_launch(void* const* d_in, const int* in_sizes, int n_in,
                              void* d_out, int out_size, void* d_ws, size_t ws_size,
                              hipStream_t stream) {
  const int* seq = (const int*)d_in[0];
  const float* xyz = (const float*)d_in[1];
  const float* orient = (const float*)d_in[2];
  const float* dihedrals = (const float*)d_in[3];
  const int* chain = (const int*)d_in[4];
  const float* amask = (const float*)d_in[5];
  const float* aa_emb = (const float*)d_in[6];
  const float* chain_emb = (const float*)d_in[7];
  const float* W1 = (const float*)d_in[8];
  const float* b1 = (const float*)d_in[9];
  const float* W2 = (const float*)d_in[10];
  const float* b2 = (const float*)d_in[11];
  const float* W3 = (const float*)d_in[12];
  const float* b3 = (const float*)d_in[13];
  const float* W4 = (const float*)d_in[14];
  const float* b4 = (const float*)d_in[15];
  float* out = (float*)d_out;
  const int n_res = in_sizes[0];  // B*L = 32768

  const int nblkH = (n_res + 255) / 256;

  // ---- ws layout ----
  char* wsp = (char*)d_ws;
  const size_t o_tabAA = 0;
  const size_t o_tabCH = o_tabAA + (size_t)N_AA * H1DIM * 4;
  const size_t o_wfhi = (o_tabCH + (size_t)10 * H1DIM * 4 + 255) & ~255ull;
  const size_t o_wflo = o_wfhi + (size_t)NFRAG_CH * 8 * 512 * 2;
  const size_t o_wl1 = o_wflo + (size_t)NFRAG_CH * 8 * 512 * 2;
  const size_t wl1_bytes = (size_t)N_AA * 3 * 16 * 512 * 2;
  const size_t o_part = (o_wl1 + wl1_bytes + 255) & ~255ull;   // nblkH*21 ints
  const size_t o_tot = (o_part + (size_t)nblkH * N_AA * 4 + 255) & ~255ull;
  const size_t o_perm = (o_tot + N_AA * 4 + 255) & ~255ull;
  const int npad_max = n_res + N_AA * 15;
  const int nblkB = (npad_max + T - 1) / T;
  const int cap = nblkB * T;
  const size_t perm_bytes = (size_t)cap * 4;
  const size_t need = o_perm + perm_bytes;

  float* tabAA = (float*)(wsp + o_tabAA);
  float* tabCH = (float*)(wsp + o_tabCH);

  if (ws_size >= need) {
    unsigned short* wf_hi = (unsigned short*)(wsp + o_wfhi);
    unsigned short* wf_lo = (unsigned short*)(wsp + o_wflo);
    unsigned short* wl1 = (unsigned short*)(wsp + o_wl1);
    int* part = (int*)(wsp + o_part);
    int* totals = (int*)(wsp + o_tot);
    unsigned int* perm = (unsigned int*)(wsp + o_perm);

    const int nprep = PR_TAB + PR_WF + PR_WL + nblkH;

    int n_arg = n_res, cap_arg = cap, nblkH_arg = nblkH;
    void* cargs[] = {(void*)&aa_emb, (void*)&chain_emb, (void*)&W1, (void*)&b1,
                     (void*)&W2, (void*)&W3, (void*)&W4, (void*)&seq,
                     (void*)&n_arg, (void*)&tabAA, (void*)&tabCH,
                     (void*)&wf_hi, (void*)&wf_lo, (void*)&wl1, (void*)&part,
                     (void*)&cap_arg, (void*)&nblkH_arg, (void*)&totals,
                     (void*)&perm};
    hipError_t cerr = hipLaunchCooperativeKernel(
        (const void*)prep_scatter, dim3(nprep), dim3(256), (void**)cargs, 0,
        stream);
    if (cerr != hipSuccess) {
      (void)hipGetLastError();  // clear error state; fall back to 2 kernels
      hipLaunchKernelGGL(prep_all, dim3(nprep), dim3(256), 0, stream, aa_emb,
                         chain_emb, W1, b1, W2, W3, W4, seq, n_res, tabAA,
                         tabCH, wf_hi, wf_lo, wl1, part);
      hipLaunchKernelGGL(scatter_pad, dim3(nblkH + N_AA + 1), dim3(256), 0,
                         stream, seq, n_res, cap, nblkH, part, totals, perm);
    }

    hipLaunchKernelGGL(residue_embed_sorted, dim3(nblkB), dim3(256), 0, stream,
                       xyz, orient, dihedrals, chain, amask, b2, b3, b4, tabAA,
                       tabCH, wl1, wf_hi, wf_lo, totals, perm, out);
  } else {
    hipLaunchKernelGGL(precompute_tables, dim3(N_AA + 10), dim3(256), 0, stream,
                       aa_emb, chain_emb, W1, b1, tabAA, tabCH);
    const int nblk = n_res / FT;
    hipLaunchKernelGGL(residue_embed_fallback, dim3(nblk), dim3(512), 0, stream,
                       seq, xyz, orient, dihedrals, chain, amask, W1, W2, b2,
                       W3, b3, W4, b4, tabAA, tabCH, out);
  }
}

// Round 18
// 58.196 us; speedup vs baseline: 1.6392x; 1.6392x over previous
//
#include <hip/hip_runtime.h>
#include <math.h>

#define N_AA 21
#define NATOM 15
#define DF 128
#define H1DIM 256
#define OFF_COORD 128
#define OFF_DIH 1073
#define OFF_CHAIN 1112
#define T 16        // rows per block (one 16-row type-pure tile)
#define FT 32       // fallback rows per block
#define DIH0 46     // (fallback only)
#define HS1 264     // h1/h3 LDS row stride (ushort)
#define HS2 136     // h2 LDS row stride (ushort)
#define FS 104      // feature LDS row stride (ushort); 96 cols used
#define NFRAG_CH 16 // frag-packed chunks for W2|W3|W4
#define INVALID_IDX 0xFFFFFFFFu
#define SSTRIDE 260 // prep LDS stage stride (fp32)

// prep role boundaries (blocks within the weight-prep segment)
#define PR_TAB 31
#define PR_WF 16
#define PR_WL 63
#define PR_NW (PR_TAB + PR_WF + PR_WL)  // 110 weight-prep blocks

typedef __attribute__((ext_vector_type(8))) short s16x8;
typedef __attribute__((ext_vector_type(4))) float f32x4;

__constant__ float c_freq[6] = {1.0f, 2.0f, 3.0f, 1.0f, 0.5f, 1.0f / 3.0f};

#define FMA4(A, S, W)            \
  A.x = fmaf((S), (W).x, A.x);   \
  A.y = fmaf((S), (W).y, A.y);   \
  A.z = fmaf((S), (W).z, A.z);   \
  A.w = fmaf((S), (W).w, A.w);

__device__ inline float bf2f(unsigned short u) {
  union { unsigned int i; float f; } x;
  x.i = (unsigned)u << 16;
  return x.f;
}
__device__ inline unsigned short f2bf(float f) {  // RNE
  unsigned int x = __float_as_uint(f);
  unsigned int r = (x + 0x7fffu + ((x >> 16) & 1u)) >> 16;
  return (unsigned short)r;
}

// ---------------- kernel A: histogram partials (plain stores) ----------------
__global__ __launch_bounds__(256) void hist_part(const int* __restrict__ seq,
                                                 int n, int* __restrict__ part) {
  __shared__ int s_h[N_AA];
  if (threadIdx.x < N_AA) s_h[threadIdx.x] = 0;
  __syncthreads();
  const int i = blockIdx.x * 256 + threadIdx.x;
  if (i < n) atomicAdd(&s_h[seq[i]], 1);
  __syncthreads();
  if (threadIdx.x < N_AA) part[blockIdx.x * N_AA + threadIdx.x] = s_h[threadIdx.x];
}

// ---------------- kernel B: weight-prep roles FUSED with scatter/pad ----------------
// blocks [0, PR_NW): tables | wfrag | wl1      (independent of part)
// blocks [PR_NW, PR_NW + 22 + nblkH): scatter_pad roles (consume part)
__global__ __launch_bounds__(256) void prep_scatter(
    const float* __restrict__ aa_emb, const float* __restrict__ chain_emb,
    const float* __restrict__ W1, const float* __restrict__ b1,
    const float* __restrict__ W2, const float* __restrict__ W3,
    const float* __restrict__ W4, const int* __restrict__ seq, int n,
    float* __restrict__ tabAA, float* __restrict__ tabCH,
    unsigned short* __restrict__ wf_hi, unsigned short* __restrict__ wf_lo,
    unsigned short* __restrict__ wl1, const int* __restrict__ part, int cap,
    int nblkH, int* __restrict__ totals, unsigned int* __restrict__ perm) {
  __shared__ float s_stage[32 * SSTRIDE];
  __shared__ int ps_tot[N_AA][9];
  __shared__ int ps_base[N_AA][9];
  __shared__ int s_tot[N_AA];
  __shared__ int s_base[N_AA];
  __shared__ int s_off[N_AA + 1];
  __shared__ int h[N_AA];
  const int bb = blockIdx.x;
  const int tid = threadIdx.x;

  if (bb < PR_NW) {
    // ---- weight-prep roles ----
    const int b = bb;
    if (b < PR_TAB) {
      const int i = tid;
      if (b < N_AA) {
        const float* e = aa_emb + b * DF;
        float acc = 0.f;
#pragma unroll 8
        for (int k = 0; k < DF; ++k) acc = fmaf(e[k], W1[k * H1DIM + i], acc);
        tabAA[b * H1DIM + i] = acc;
      } else {
        const int c = b - N_AA;
        const float* e = chain_emb + c * DF;
        float acc = b1[i];
#pragma unroll 8
        for (int k = 0; k < DF; ++k)
          acc = fmaf(e[k], W1[(OFF_CHAIN + k) * H1DIM + i], acc);
        tabCH[c * H1DIM + i] = acc;
      }
    } else if (b < PR_TAB + PR_WF) {
      const int cgb = b - PR_TAB;
      const float* W;
      int kbase;
      if (cgb < 8) { W = W2; kbase = cgb * 32; }
      else if (cgb < 12) { W = W3; kbase = (cgb - 8) * 32; }
      else { W = W4; kbase = (cgb - 12) * 32; }
      for (int idx = tid; idx < 32 * 128; idx += 256) {
        const int k = idx >> 7, col = idx & 127;
        s_stage[k * SSTRIDE + col] = W[(kbase + k) * DF + col];
      }
      __syncthreads();
      for (int e = tid; e < 8 * 512; e += 256) {
        const int rem = e & 511;
        const int nt = e >> 9;
        const int l = rem >> 3, jj = rem & 7;
        const int col = nt * 16 + (l & 15);
        const int k = (l >> 4) * 8 + jj;
        const float v = s_stage[k * SSTRIDE + col];
        const unsigned short hh = f2bf(v);
        wf_hi[(size_t)cgb * 4096 + e] = hh;
        wf_lo[(size_t)cgb * 4096 + e] = f2bf(v - bf2f(hh));
      }
    } else {
      const int b2 = b - PR_TAB - PR_WF;  // 0..62
      const int t = b2 / 3, c = b2 % 3;
      for (int idx = tid; idx < 32 * 256; idx += 256) {
        const int kp = idx >> 8, col = idx & 255;
        const int k = c * 32 + kp;
        float v = 0.f;
        if (k < 45) v = W1[(OFF_COORD + t * 45 + k) * H1DIM + col];
        else if (k < 84) v = W1[(OFF_DIH + (k - 45)) * H1DIM + col];
        s_stage[kp * SSTRIDE + col] = v;
      }
      __syncthreads();
      for (int e = tid; e < 16 * 512; e += 256) {
        const int rem = e & 511;
        const int nt = e >> 9;
        const int l = rem >> 3, j = rem & 7;
        const int col = nt * 16 + (l & 15);
        const int kp = (l >> 4) * 8 + j;
        wl1[(size_t)b2 * 8192 + e] = f2bf(s_stage[kp * SSTRIDE + col]);
      }
    }
    return;
  }

  // ---- scatter/pad roles (b' in [0, 22 + nblkH)) ----
  const int b = bb - PR_NW;
  const int myhb = b - N_AA - 1;  // >=0 only for scatter blocks
  const int segLen = (nblkH + 7) >> 3;
  if (tid < N_AA * 8) {
    const int t = tid >> 3, seg = tid & 7;
    int tot = 0, bas = 0;
    for (int j = 0; j < segLen; ++j) {
      const int hb = seg * segLen + j;
      if (hb < nblkH) {
        const int v = part[hb * N_AA + t];
        tot += v;
        if (hb < myhb) bas += v;
      }
    }
    ps_tot[t][seg] = tot;
    ps_base[t][seg] = bas;
  }
  __syncthreads();
  if (tid < N_AA) {
    int tot = 0, bas = 0;
#pragma unroll
    for (int s = 0; s < 8; ++s) { tot += ps_tot[tid][s]; bas += ps_base[tid][s]; }
    s_tot[tid] = tot;
    s_base[tid] = bas;
  }
  __syncthreads();
  if (tid == 0) {
    int acc = 0;
    s_off[0] = 0;
    for (int tt = 0; tt < N_AA; ++tt) {
      acc += (s_tot[tt] + 15) & ~15;
      s_off[tt + 1] = acc;
    }
  }
  __syncthreads();
  if (b < N_AA) {
    const int padstart = s_off[b] + s_tot[b];
    const int padcnt = s_off[b + 1] - padstart;
    if (tid < padcnt) perm[padstart + tid] = INVALID_IDX;
  } else if (b == N_AA) {
    for (int i = s_off[N_AA] + tid; i < cap; i += 256) perm[i] = INVALID_IDX;
    if (tid < N_AA) totals[tid] = s_tot[tid];
  } else {
    if (tid < N_AA) h[tid] = 0;
    __syncthreads();
    const int i = myhb * 256 + tid;
    if (i < n) {
      const int tt = seq[i];
      const int slot = atomicAdd(&h[tt], 1);
      perm[s_off[tt] + s_base[tt] + slot] = (unsigned int)i;
    }
  }
}

// ---------------- main kernel: 16-row tile, 4 waves; hi-only activations (r16-exact) ----------------
__global__ __launch_bounds__(256, 8) void residue_embed_sorted(
    const float* __restrict__ xyz, const float* __restrict__ orient,
    const float* __restrict__ dihedrals, const int* __restrict__ chain_idx,
    const float* __restrict__ amask, const float* __restrict__ b2,
    const float* __restrict__ b3, const float* __restrict__ b4,
    const float* __restrict__ tabAA, const float* __restrict__ tabCH,
    const unsigned short* __restrict__ wl1, const unsigned short* __restrict__ wf_hi,
    const unsigned short* __restrict__ wf_lo, const int* __restrict__ totals,
    const unsigned int* __restrict__ perm, float* __restrict__ out) {
  __shared__ unsigned short s_h1hi[T][HS1];  // h1 hi; later h3 hi (cols 0..127)
  __shared__ __align__(16) char s_u[T * HS2 * 2];  // feat-hi [16][FS] | h2-hi [16][HS2]
  __shared__ unsigned int s_g[T];
  __shared__ int s_c[T];
  __shared__ int s_off[N_AA + 1];
  __shared__ int s_cnt[N_AA];

  unsigned short (*s_fh)[FS] = (unsigned short(*)[FS])s_u;
  unsigned short (*s_h2hi)[HS2] = (unsigned short(*)[HS2])s_u;

  const int tid = threadIdx.x;
  const int base = blockIdx.x * T;

  if (tid < T) {
    const unsigned int g = perm[base + tid];
    s_g[tid] = g;
    s_c[tid] = (g != INVALID_IDX) ? chain_idx[g] : 0;
  }
  if (tid >= 32 && tid < 32 + N_AA) s_cnt[tid - 32] = totals[tid - 32];
  __syncthreads();
  if (tid == 0) {
    int acc = 0;
    s_off[0] = 0;
    for (int t2 = 0; t2 < N_AA; ++t2) {
      acc += (s_cnt[t2] + 15) & ~15;
      s_off[t2 + 1] = acc;
    }
  }

  // ---- phase 0: gather via s_g; features -> bf16 LDS (hi only) ----
  for (int idx = tid; idx < T * 45; idx += 256) {
    const int r = idx / 45, k = idx % 45;
    const int a = k / 3, i = k % 3;
    const unsigned int g = s_g[r];
    float v = 0.f;
    if (g != INVALID_IDX) {
      const float* X = xyz + (size_t)g * 45;
      const float* R = orient + (size_t)g * 9;
      const float m = amask[(size_t)g * NATOM + a];
#pragma unroll
      for (int j = 0; j < 3; ++j)
        v = fmaf(R[j * 3 + i], X[a * 3 + j] - X[3 + j], v);  // CA = atom 1
      v *= m;
    }
    s_fh[r][k] = f2bf(v);
  }
  for (int idx = tid; idx < T * 39; idx += 256) {
    const int r = idx / 39, kk = idx % 39;
    const int d = kk / 13, m = kk % 13;
    const unsigned int g = s_g[r];
    float v = 0.f;
    if (g != INVALID_IDX) {
      const float x = dihedrals[(size_t)g * 3 + d];
      if (m == 0) v = x;
      else if (m <= 6) v = sinf(c_freq[m - 1] * x);
      else v = cosf(c_freq[m - 7] * x);
    }
    s_fh[r][45 + kk] = f2bf(v);
  }
  for (int idx = tid; idx < T * 12; idx += 256) {  // zero pad k 84..95
    const int r = idx / 12, k = 84 + idx % 12;
    s_fh[r][k] = 0;
  }
  __syncthreads();  // features + s_off visible

  // ---- MFMA tiling constants (4 waves: wave = col group) ----
  const int l = tid & 63;
  const int nc = tid >> 6;           // wave 0..3
  const int nc0 = nc * 32;           // layers 2-4 col base (DF=128)
  const int ar = l & 15;             // A row (residue)
  const int kb = (l >> 4) * 8;
  const int drow = (l >> 4) * 4;
  const size_t fbase = (size_t)(2 * nc) * 512 + (size_t)l * 8;

  // tile type (whole block is one type-pure 16-tile)
  int ty = 0;
#pragma unroll
  for (int t2 = 1; t2 < N_AA; ++t2)
    if (base >= s_off[t2]) ty = t2;

  // ---- layer 1: h1 = relu(feat96 @ W1type + tabAA[ty] + tabCH[chain]) ----
  {
    f32x4 acc[4] = {{0.f, 0.f, 0.f, 0.f}, {0.f, 0.f, 0.f, 0.f},
                    {0.f, 0.f, 0.f, 0.f}, {0.f, 0.f, 0.f, 0.f}};
    s16x8 ah[3];
#pragma unroll
    for (int c = 0; c < 3; ++c)
      ah[c] = *(const s16x8*)(&s_fh[ar][c * 32 + kb]);
    const unsigned short* pB = wl1 + ((size_t)ty * 48 + 4 * nc) * 512 + (size_t)l * 8;
#pragma unroll
    for (int c = 0; c < 3; ++c) {
#pragma unroll
      for (int nt2 = 0; nt2 < 4; ++nt2) {
        const s16x8 bb = *(const s16x8*)(pB + ((size_t)c * 16 + nt2) * 512);
        acc[nt2] = __builtin_amdgcn_mfma_f32_16x16x32_bf16(ah[c], bb, acc[nt2], 0, 0, 0);
      }
    }
    __syncthreads();  // all feature reads done before h1 store / later h2 overwrite
#pragma unroll
    for (int nt2 = 0; nt2 < 4; ++nt2) {
      const int col0 = nc * 64 + nt2 * 16 + (l & 15);
      const float ta = tabAA[ty * H1DIM + col0];
#pragma unroll
      for (int reg = 0; reg < 4; ++reg) {
        const int row = drow + reg;
        float v = acc[nt2][reg] + ta + tabCH[s_c[row] * H1DIM + col0];
        v = fmaxf(v, 0.f);
        s_h1hi[row][col0] = f2bf(v);
      }
    }
  }
  __syncthreads();  // h1 visible

#define MFMA_LAYER(NCHUNK, CG0, SRCH, SSTR, BPTR, EPI)                           \
  do {                                                                           \
    f32x4 acc0 = {0.f, 0.f, 0.f, 0.f}, acc1 = {0.f, 0.f, 0.f, 0.f};             \
    const unsigned short* ph = wf_hi + (size_t)(CG0)*4096 + fbase;               \
    const unsigned short* pl = wf_lo + (size_t)(CG0)*4096 + fbase;               \
    _Pragma("unroll 2")                                                          \
    for (int c = 0; c < (NCHUNK); ++c) {                                         \
      const s16x8 b0h = *(const s16x8*)(ph + (size_t)c * 4096);                  \
      const s16x8 b1h = *(const s16x8*)(ph + (size_t)c * 4096 + 512);            \
      const s16x8 b0l = *(const s16x8*)(pl + (size_t)c * 4096);                  \
      const s16x8 b1l = *(const s16x8*)(pl + (size_t)c * 4096 + 512);            \
      const int ko = c * 32 + kb;                                                \
      const s16x8 ah = *(const s16x8*)((SRCH) + ar * (SSTR) + ko);               \
      acc0 = __builtin_amdgcn_mfma_f32_16x16x32_bf16(ah, b0h, acc0, 0, 0, 0);    \
      acc1 = __builtin_amdgcn_mfma_f32_16x16x32_bf16(ah, b1h, acc1, 0, 0, 0);    \
      acc0 = __builtin_amdgcn_mfma_f32_16x16x32_bf16(ah, b0l, acc0, 0, 0, 0);    \
      acc1 = __builtin_amdgcn_mfma_f32_16x16x32_bf16(ah, b1l, acc1, 0, 0, 0);    \
    }                                                                            \
    const float bias0 = (BPTR)[nc0 + (l & 15)];                                  \
    const float bias1 = (BPTR)[nc0 + 16 + (l & 15)];                             \
    EPI                                                                          \
  } while (0)

#define EPI_HIDDEN(DH, DSTR)                                                     \
  {                                                                              \
    _Pragma("unroll")                                                            \
    for (int reg = 0; reg < 4; ++reg) {                                          \
      const int row = drow + reg;                                                \
      float v0 = fmaxf(acc0[reg] + bias0, 0.f);                                  \
      float v1 = fmaxf(acc1[reg] + bias1, 0.f);                                  \
      (DH)[row * (DSTR) + nc0 + (l & 15)] = f2bf(v0);                            \
      (DH)[row * (DSTR) + nc0 + 16 + (l & 15)] = f2bf(v1);                       \
    }                                                                            \
  }

  // ---- layer 2: K=256 (h2 overwrites feature region of s_u) ----
  MFMA_LAYER(8, 0, &s_h1hi[0][0], HS1, b2, EPI_HIDDEN(&s_h2hi[0][0], HS2));
  __syncthreads();

  // ---- layer 3: K=128 -> overwrite s_h1 ----
  MFMA_LAYER(4, 8, &s_h2hi[0][0], HS2, b3, EPI_HIDDEN(&s_h1hi[0][0], HS1));
  __syncthreads();

  // ---- layer 4: K=128, scatter-store via perm ----
  MFMA_LAYER(4, 12, &s_h1hi[0][0], HS1, b4, {
    _Pragma("unroll")
    for (int reg = 0; reg < 4; ++reg) {
      const unsigned int g = s_g[drow + reg];
      if (g != INVALID_IDX) {
        out[(size_t)g * DF + nc0 + (l & 15)] = acc0[reg] + bias0;
        out[(size_t)g * DF + nc0 + 16 + (l & 15)] = acc1[reg] + bias1;
      }
    }
  });
}

// ---------------- fp32 fallback path kernels ----------------
__global__ __launch_bounds__(256) void precompute_tables(
    const float* __restrict__ aa_emb, const float* __restrict__ chain_emb,
    const float* __restrict__ W1, const float* __restrict__ b1,
    float* __restrict__ tabAA, float* __restrict__ tabCH) {
  const int i = threadIdx.x;
  const int b = blockIdx.x;
  if (b < N_AA) {
    const float* e = aa_emb + b * DF;
    float acc = 0.f;
#pragma unroll 8
    for (int k = 0; k < DF; ++k) acc = fmaf(e[k], W1[k * H1DIM + i], acc);
    tabAA[b * H1DIM + i] = acc;
  } else {
    const int c = b - N_AA;
    const float* e = chain_emb + c * DF;
    float acc = b1[i];
#pragma unroll 8
    for (int k = 0; k < DF; ++k)
      acc = fmaf(e[k], W1[(OFF_CHAIN + k) * H1DIM + i], acc);
    tabCH[c * H1DIM + i] = acc;
  }
}

__global__ __launch_bounds__(512, 4) void residue_embed_fallback(
    const int* __restrict__ seq_idx, const float* __restrict__ xyz,
    const float* __restrict__ orient, const float* __restrict__ dihedrals,
    const int* __restrict__ chain_idx, const float* __restrict__ amask,
    const float* __restrict__ W1, const float* __restrict__ W2,
    const float* __restrict__ b2, const float* __restrict__ W3,
    const float* __restrict__ b3, const float* __restrict__ W4,
    const float* __restrict__ b4, const float* __restrict__ tabAA,
    const float* __restrict__ tabCH, float* __restrict__ out) {
  __shared__ float s_h1[FT][260];
  __shared__ float s_buf2[FT][132];
  __shared__ float s_w[32 * DF];
  __shared__ int s_t[FT];
  __shared__ int s_c[FT];

  const int tid = threadIdx.x;
  const int base = blockIdx.x * FT;

  if (tid < FT) {
    s_t[tid] = seq_idx[base + tid];
    s_c[tid] = chain_idx[base + tid];
  }
  for (int idx = tid; idx < FT * 45; idx += 512) {
    const int r = idx / 45, k = idx % 45;
    const int a = k / 3, i = k % 3;
    const int g = base + r;
    const float* X = xyz + g * 45;
    const float* R = orient + g * 9;
    const float m = amask[g * NATOM + a];
    float v = 0.f;
#pragma unroll
    for (int j = 0; j < 3; ++j)
      v = fmaf(R[j * 3 + i], X[a * 3 + j] - X[3 + j], v);
    s_buf2[r][k] = v * m;
  }
  for (int idx = tid; idx < FT * 39; idx += 512) {
    const int r = idx / 39, k = idx % 39;
    const int d = k / 13, m = k % 13;
    const float x = dihedrals[(base + r) * 3 + d];
    float v;
    if (m == 0) v = x;
    else if (m <= 6) v = sinf(c_freq[m - 1] * x);
    else v = cosf(c_freq[m - 7] * x);
    s_buf2[r][DIH0 + k] = v;
  }
  __syncthreads();
  {
    const int i0 = (tid & 63) * 4;
    const int r0 = (tid >> 6) * 4;
    float4 acc[4];
#pragma unroll
    for (int rr = 0; rr < 4; ++rr) {
      const int t = s_t[r0 + rr], c = s_c[r0 + rr];
      const float4 a = *(const float4*)(tabAA + t * H1DIM + i0);
      const float4 b = *(const float4*)(tabCH + c * H1DIM + i0);
      acc[rr].x = a.x + b.x; acc[rr].y = a.y + b.y;
      acc[rr].z = a.z + b.z; acc[rr].w = a.w + b.w;
    }
#pragma unroll 3
    for (int k = 0; k < 39; ++k) {
      const float4 wv = *(const float4*)(W1 + (OFF_DIH + k) * H1DIM + i0);
#pragma unroll
      for (int rr = 0; rr < 4; ++rr) {
        FMA4(acc[rr], s_buf2[r0 + rr][DIH0 + k], wv);
      }
    }
    const float* wp[4];
#pragma unroll
    for (int rr = 0; rr < 4; ++rr)
      wp[rr] = W1 + (OFF_COORD + s_t[r0 + rr] * 45) * H1DIM + i0;
    for (int k = 0; k < 45; ++k) {
#pragma unroll
      for (int rr = 0; rr < 4; ++rr) {
        const float4 wv = *(const float4*)(wp[rr] + k * H1DIM);
        FMA4(acc[rr], s_buf2[r0 + rr][k], wv);
      }
    }
#pragma unroll
    for (int rr = 0; rr < 4; ++rr) {
      float4 v;
      v.x = fmaxf(acc[rr].x, 0.f); v.y = fmaxf(acc[rr].y, 0.f);
      v.z = fmaxf(acc[rr].z, 0.f); v.w = fmaxf(acc[rr].w, 0.f);
      *(float4*)(&s_h1[r0 + rr][i0]) = v;
    }
  }
  const int j0 = (tid & 31) * 4;
  const int r2 = (tid >> 5) * 2;
#define FB_LAYER(NCH, WSRC, SRC, BPTR, STORE)                               \
  do {                                                                      \
    const float4 bb = *(const float4*)((BPTR) + j0);                        \
    float4 acc0 = bb, acc1 = bb;                                            \
    for (int c = 0; c < (NCH); ++c) {                                       \
      __syncthreads();                                                      \
      {                                                                     \
        const float* src = (WSRC) + c * 32 * DF;                            \
        const int idx = tid * 8;                                            \
        *(float4*)(&s_w[idx]) = *(const float4*)(src + idx);                \
        *(float4*)(&s_w[idx + 4]) = *(const float4*)(src + idx + 4);        \
      }                                                                     \
      __syncthreads();                                                      \
      const int kb2 = c * 32;                                               \
      _Pragma("unroll")                                                     \
      for (int kk = 0; kk < 32; kk += 4) {                                  \
        const float4 a0 = *(const float4*)(&(SRC)[r2][kb2 + kk]);           \
        const float4 a1 = *(const float4*)(&(SRC)[r2 + 1][kb2 + kk]);       \
        const float4 w0 = *(const float4*)(&s_w[(kk + 0) * DF + j0]);       \
        const float4 w1 = *(const float4*)(&s_w[(kk + 1) * DF + j0]);       \
        const float4 w2 = *(const float4*)(&s_w[(kk + 2) * DF + j0]);       \
        const float4 w3 = *(const float4*)(&s_w[(kk + 3) * DF + j0]);       \
        FMA4(acc0, a0.x, w0); FMA4(acc1, a1.x, w0);                         \
        FMA4(acc0, a0.y, w1); FMA4(acc1, a1.y, w1);                         \
        FMA4(acc0, a0.z, w2); FMA4(acc1, a1.z, w2);                         \
        FMA4(acc0, a0.w, w3); FMA4(acc1, a1.w, w3);                         \
      }                                                                     \
    }                                                                       \
    STORE                                                                   \
  } while (0)
#define RELU_STORE(DST)                                                     \
  {                                                                         \
    float4 v0, v1;                                                          \
    v0.x = fmaxf(acc0.x, 0.f); v0.y = fmaxf(acc0.y, 0.f);                   \
    v0.z = fmaxf(acc0.z, 0.f); v0.w = fmaxf(acc0.w, 0.f);                   \
    v1.x = fmaxf(acc1.x, 0.f); v1.y = fmaxf(acc1.y, 0.f);                   \
    v1.z = fmaxf(acc1.z, 0.f); v1.w = fmaxf(acc1.w, 0.f);                   \
    *(float4*)(&(DST)[r2][j0]) = v0;                                        \
    *(float4*)(&(DST)[r2 + 1][j0]) = v1;                                    \
  }
  FB_LAYER(8, W2, s_h1, b2, RELU_STORE(s_buf2));
  FB_LAYER(4, W3, s_buf2, b3, RELU_STORE(s_h1));
  FB_LAYER(4, W4, s_h1, b4, {
    *(float4*)(out + (size_t)(base + r2) * DF + j0) = acc0;
    *(float4*)(out + (size_t)(base + r2 + 1) * DF + j0) = acc1;
  });
}

extern "C" void kernel_launch(void* const* d_in, const int* in_sizes, int n_in,
                              void* d_out, int out_size, void* d_ws, size_t ws_size,
                              hipStream_t stream) {
  const int* seq = (const int*)d_in[0];
  const float* xyz = (const float*)d_in[1];
  const float* orient = (const float*)d_in[2];
  const float* dihedrals = (const float*)d_in[3];
  const int* chain = (const int*)d_in[4];
  const float* amask = (const float*)d_in[5];
  const float* aa_emb = (const float*)d_in[6];
  const float* chain_emb = (const float*)d_in[7];
  const float* W1 = (const float*)d_in[8];
  const float* b1 = (const float*)d_in[9];
  const float* W2 = (const float*)d_in[10];
  const float* b2 = (const float*)d_in[11];
  const float* W3 = (const float*)d_in[12];
  const float* b3 = (const float*)d_in[13];
  const float* W4 = (const float*)d_in[14];
  const float* b4 = (const float*)d_in[15];
  float* out = (float*)d_out;
  const int n_res = in_sizes[0];  // B*L = 32768

  const int nblkH = (n_res + 255) / 256;

  // ---- ws layout ----
  char* wsp = (char*)d_ws;
  const size_t o_tabAA = 0;
  const size_t o_tabCH = o_tabAA + (size_t)N_AA * H1DIM * 4;
  const size_t o_wfhi = (o_tabCH + (size_t)10 * H1DIM * 4 + 255) & ~255ull;
  const size_t o_wflo = o_wfhi + (size_t)NFRAG_CH * 8 * 512 * 2;
  const size_t o_wl1 = o_wflo + (size_t)NFRAG_CH * 8 * 512 * 2;
  const size_t wl1_bytes = (size_t)N_AA * 3 * 16 * 512 * 2;
  const size_t o_part = (o_wl1 + wl1_bytes + 255) & ~255ull;   // nblkH*21 ints
  const size_t o_tot = (o_part + (size_t)nblkH * N_AA * 4 + 255) & ~255ull;
  const size_t o_perm = (o_tot + N_AA * 4 + 255) & ~255ull;
  const int npad_max = n_res + N_AA * 15;
  const int nblkB = (npad_max + T - 1) / T;
  const int cap = nblkB * T;
  const size_t perm_bytes = (size_t)cap * 4;
  const size_t need = o_perm + perm_bytes;

  float* tabAA = (float*)(wsp + o_tabAA);
  float* tabCH = (float*)(wsp + o_tabCH);

  if (ws_size >= need) {
    unsigned short* wf_hi = (unsigned short*)(wsp + o_wfhi);
    unsigned short* wf_lo = (unsigned short*)(wsp + o_wflo);
    unsigned short* wl1 = (unsigned short*)(wsp + o_wl1);
    int* part = (int*)(wsp + o_part);
    int* totals = (int*)(wsp + o_tot);
    unsigned int* perm = (unsigned int*)(wsp + o_perm);

    hipLaunchKernelGGL(hist_part, dim3(nblkH), dim3(256), 0, stream, seq,
                       n_res, part);

    hipLaunchKernelGGL(prep_scatter, dim3(PR_NW + nblkH + N_AA + 1), dim3(256),
                       0, stream, aa_emb, chain_emb, W1, b1, W2, W3, W4, seq,
                       n_res, tabAA, tabCH, wf_hi, wf_lo, wl1, part, cap,
                       nblkH, totals, perm);

    hipLaunchKernelGGL(residue_embed_sorted, dim3(nblkB), dim3(256), 0, stream,
                       xyz, orient, dihedrals, chain, amask, b2, b3, b4, tabAA,
                       tabCH, wl1, wf_hi, wf_lo, totals, perm, out);
  } else {
    hipLaunchKernelGGL(precompute_tables, dim3(N_AA + 10), dim3(256), 0, stream,
                       aa_emb, chain_emb, W1, b1, tabAA, tabCH);
    const int nblk = n_res / FT;
    hipLaunchKernelGGL(residue_embed_fallback, dim3(nblk), dim3(512), 0, stream,
                       seq, xyz, orient, dihedrals, chain, amask, W1, W2, b2,
                       W3, b3, W4, b4, tabAA, tabCH, out);
  }
}

// Round 19
// 51.388 us; speedup vs baseline: 1.8563x; 1.1325x over previous
//
#include <hip/hip_runtime.h>
#include <math.h>

#define N_AA 21
#define NATOM 15
#define DF 128
#define H1DIM 256
#define OFF_COORD 128
#define OFF_DIH 1073
#define OFF_CHAIN 1112
#define T 32        // rows per block (two 16-row type-pure halves share B-frags)
#define FT 32       // fallback rows per block
#define DIH0 46     // (fallback only)
#define HS1 264     // h1/h3 LDS row stride (ushort)
#define HS2 136     // h2 LDS row stride (ushort)
#define FS 104      // feature LDS row stride (ushort); 96 cols used
#define NFRAG_CH 16 // frag-packed chunks for W2|W3|W4
#define INVALID_IDX 0xFFFFFFFFu
#define SSTRIDE 260 // prep LDS stage stride (fp32)

// prep role boundaries (blocks within the weight-prep segment)
#define PR_TAB 31
#define PR_WF 16
#define PR_WL 63
#define PR_NW (PR_TAB + PR_WF + PR_WL)  // 110 weight-prep blocks

typedef __attribute__((ext_vector_type(8))) short s16x8;
typedef __attribute__((ext_vector_type(4))) float f32x4;

__constant__ float c_freq[6] = {1.0f, 2.0f, 3.0f, 1.0f, 0.5f, 1.0f / 3.0f};

#define FMA4(A, S, W)            \
  A.x = fmaf((S), (W).x, A.x);   \
  A.y = fmaf((S), (W).y, A.y);   \
  A.z = fmaf((S), (W).z, A.z);   \
  A.w = fmaf((S), (W).w, A.w);

__device__ inline float bf2f(unsigned short u) {
  union { unsigned int i; float f; } x;
  x.i = (unsigned)u << 16;
  return x.f;
}
__device__ inline unsigned short f2bf(float f) {  // RNE
  unsigned int x = __float_as_uint(f);
  unsigned int r = (x + 0x7fffu + ((x >> 16) & 1u)) >> 16;
  return (unsigned short)r;
}

// ---------------- kernel A: histogram partials (plain stores) ----------------
__global__ __launch_bounds__(256) void hist_part(const int* __restrict__ seq,
                                                 int n, int* __restrict__ part) {
  __shared__ int s_h[N_AA];
  if (threadIdx.x < N_AA) s_h[threadIdx.x] = 0;
  __syncthreads();
  const int i = blockIdx.x * 256 + threadIdx.x;
  if (i < n) atomicAdd(&s_h[seq[i]], 1);
  __syncthreads();
  if (threadIdx.x < N_AA) part[blockIdx.x * N_AA + threadIdx.x] = s_h[threadIdx.x];
}

// ---------------- kernel B: weight-prep roles FUSED with scatter/pad ----------------
__global__ __launch_bounds__(256) void prep_scatter(
    const float* __restrict__ aa_emb, const float* __restrict__ chain_emb,
    const float* __restrict__ W1, const float* __restrict__ b1,
    const float* __restrict__ W2, const float* __restrict__ W3,
    const float* __restrict__ W4, const int* __restrict__ seq, int n,
    float* __restrict__ tabAA, float* __restrict__ tabCH,
    unsigned short* __restrict__ wf_hi, unsigned short* __restrict__ wf_lo,
    unsigned short* __restrict__ wl1, const int* __restrict__ part, int cap,
    int nblkH, int* __restrict__ totals, unsigned int* __restrict__ perm) {
  __shared__ float s_stage[32 * SSTRIDE];
  __shared__ int ps_tot[N_AA][9];
  __shared__ int ps_base[N_AA][9];
  __shared__ int s_tot[N_AA];
  __shared__ int s_base[N_AA];
  __shared__ int s_off[N_AA + 1];
  __shared__ int h[N_AA];
  const int bb = blockIdx.x;
  const int tid = threadIdx.x;

  if (bb < PR_NW) {
    const int b = bb;
    if (b < PR_TAB) {
      const int i = tid;
      if (b < N_AA) {
        const float* e = aa_emb + b * DF;
        float acc = 0.f;
#pragma unroll 8
        for (int k = 0; k < DF; ++k) acc = fmaf(e[k], W1[k * H1DIM + i], acc);
        tabAA[b * H1DIM + i] = acc;
      } else {
        const int c = b - N_AA;
        const float* e = chain_emb + c * DF;
        float acc = b1[i];
#pragma unroll 8
        for (int k = 0; k < DF; ++k)
          acc = fmaf(e[k], W1[(OFF_CHAIN + k) * H1DIM + i], acc);
        tabCH[c * H1DIM + i] = acc;
      }
    } else if (b < PR_TAB + PR_WF) {
      const int cgb = b - PR_TAB;
      const float* W;
      int kbase;
      if (cgb < 8) { W = W2; kbase = cgb * 32; }
      else if (cgb < 12) { W = W3; kbase = (cgb - 8) * 32; }
      else { W = W4; kbase = (cgb - 12) * 32; }
      for (int idx = tid; idx < 32 * 128; idx += 256) {
        const int k = idx >> 7, col = idx & 127;
        s_stage[k * SSTRIDE + col] = W[(kbase + k) * DF + col];
      }
      __syncthreads();
      for (int e = tid; e < 8 * 512; e += 256) {
        const int rem = e & 511;
        const int nt = e >> 9;
        const int l = rem >> 3, jj = rem & 7;
        const int col = nt * 16 + (l & 15);
        const int k = (l >> 4) * 8 + jj;
        const float v = s_stage[k * SSTRIDE + col];
        const unsigned short hh = f2bf(v);
        wf_hi[(size_t)cgb * 4096 + e] = hh;
        wf_lo[(size_t)cgb * 4096 + e] = f2bf(v - bf2f(hh));
      }
    } else {
      const int b2 = b - PR_TAB - PR_WF;  // 0..62
      const int t = b2 / 3, c = b2 % 3;
      for (int idx = tid; idx < 32 * 256; idx += 256) {
        const int kp = idx >> 8, col = idx & 255;
        const int k = c * 32 + kp;
        float v = 0.f;
        if (k < 45) v = W1[(OFF_COORD + t * 45 + k) * H1DIM + col];
        else if (k < 84) v = W1[(OFF_DIH + (k - 45)) * H1DIM + col];
        s_stage[kp * SSTRIDE + col] = v;
      }
      __syncthreads();
      for (int e = tid; e < 16 * 512; e += 256) {
        const int rem = e & 511;
        const int nt = e >> 9;
        const int l = rem >> 3, j = rem & 7;
        const int col = nt * 16 + (l & 15);
        const int kp = (l >> 4) * 8 + j;
        wl1[(size_t)b2 * 8192 + e] = f2bf(s_stage[kp * SSTRIDE + col]);
      }
    }
    return;
  }

  // ---- scatter/pad roles ----
  const int b = bb - PR_NW;
  const int myhb = b - N_AA - 1;
  const int segLen = (nblkH + 7) >> 3;
  if (tid < N_AA * 8) {
    const int t = tid >> 3, seg = tid & 7;
    int tot = 0, bas = 0;
    for (int j = 0; j < segLen; ++j) {
      const int hb = seg * segLen + j;
      if (hb < nblkH) {
        const int v = part[hb * N_AA + t];
        tot += v;
        if (hb < myhb) bas += v;
      }
    }
    ps_tot[t][seg] = tot;
    ps_base[t][seg] = bas;
  }
  __syncthreads();
  if (tid < N_AA) {
    int tot = 0, bas = 0;
#pragma unroll
    for (int s = 0; s < 8; ++s) { tot += ps_tot[tid][s]; bas += ps_base[tid][s]; }
    s_tot[tid] = tot;
    s_base[tid] = bas;
  }
  __syncthreads();
  if (tid == 0) {
    int acc = 0;
    s_off[0] = 0;
    for (int tt = 0; tt < N_AA; ++tt) {
      acc += (s_tot[tt] + 15) & ~15;
      s_off[tt + 1] = acc;
    }
  }
  __syncthreads();
  if (b < N_AA) {
    const int padstart = s_off[b] + s_tot[b];
    const int padcnt = s_off[b + 1] - padstart;
    if (tid < padcnt) perm[padstart + tid] = INVALID_IDX;
  } else if (b == N_AA) {
    for (int i = s_off[N_AA] + tid; i < cap; i += 256) perm[i] = INVALID_IDX;
    if (tid < N_AA) totals[tid] = s_tot[tid];
  } else {
    if (tid < N_AA) h[tid] = 0;
    __syncthreads();
    const int i = myhb * 256 + tid;
    if (i < n) {
      const int tt = seq[i];
      const int slot = atomicAdd(&h[tt], 1);
      perm[s_off[tt] + s_base[tt] + slot] = (unsigned int)i;
    }
  }
}

// ---------------- main kernel: 32 rows (2 halves share B-frags), hi-only activations ----------------
__global__ __launch_bounds__(256, 6) void residue_embed_sorted(
    const float* __restrict__ xyz, const float* __restrict__ orient,
    const float* __restrict__ dihedrals, const int* __restrict__ chain_idx,
    const float* __restrict__ amask, const float* __restrict__ b2,
    const float* __restrict__ b3, const float* __restrict__ b4,
    const float* __restrict__ tabAA, const float* __restrict__ tabCH,
    const unsigned short* __restrict__ wl1, const unsigned short* __restrict__ wf_hi,
    const unsigned short* __restrict__ wf_lo, const int* __restrict__ totals,
    const unsigned int* __restrict__ perm, float* __restrict__ out) {
  __shared__ unsigned short s_h1hi[T][HS1];  // h1 hi; later h3 hi (cols 0..127)
  __shared__ __align__(16) char s_u[T * HS2 * 2];  // feat-hi [32][FS] | h2-hi [32][HS2]
  __shared__ unsigned int s_g[T];
  __shared__ int s_c[T];
  __shared__ int s_off[N_AA + 1];
  __shared__ int s_cnt[N_AA];

  unsigned short (*s_fh)[FS] = (unsigned short(*)[FS])s_u;
  unsigned short (*s_h2hi)[HS2] = (unsigned short(*)[HS2])s_u;

  const int tid = threadIdx.x;
  const int base = blockIdx.x * T;

  if (tid < T) {
    const unsigned int g = perm[base + tid];
    s_g[tid] = g;
    s_c[tid] = (g != INVALID_IDX) ? chain_idx[g] : 0;
  }
  if (tid >= 64 && tid < 64 + N_AA) s_cnt[tid - 64] = totals[tid - 64];
  __syncthreads();
  if (tid == 0) {
    int acc = 0;
    s_off[0] = 0;
    for (int t2 = 0; t2 < N_AA; ++t2) {
      acc += (s_cnt[t2] + 15) & ~15;
      s_off[t2 + 1] = acc;
    }
  }

  // ---- phase 0: gather via s_g; features -> bf16 LDS (hi only) ----
  for (int idx = tid; idx < T * 45; idx += 256) {
    const int r = idx / 45, k = idx % 45;
    const int a = k / 3, i = k % 3;
    const unsigned int g = s_g[r];
    float v = 0.f;
    if (g != INVALID_IDX) {
      const float* X = xyz + (size_t)g * 45;
      const float* R = orient + (size_t)g * 9;
      const float m = amask[(size_t)g * NATOM + a];
#pragma unroll
      for (int j = 0; j < 3; ++j)
        v = fmaf(R[j * 3 + i], X[a * 3 + j] - X[3 + j], v);  // CA = atom 1
      v *= m;
    }
    s_fh[r][k] = f2bf(v);
  }
  for (int idx = tid; idx < T * 39; idx += 256) {
    const int r = idx / 39, kk = idx % 39;
    const int d = kk / 13, m = kk % 13;
    const unsigned int g = s_g[r];
    float v = 0.f;
    if (g != INVALID_IDX) {
      const float x = dihedrals[(size_t)g * 3 + d];
      if (m == 0) v = x;
      else if (m <= 6) v = sinf(c_freq[m - 1] * x);
      else v = cosf(c_freq[m - 7] * x);
    }
    s_fh[r][45 + kk] = f2bf(v);
  }
  for (int idx = tid; idx < T * 12; idx += 256) {  // zero pad k 84..95
    const int r = idx / 12, k = 84 + idx % 12;
    s_fh[r][k] = 0;
  }
  __syncthreads();  // features + s_off visible

  // ---- MFMA tiling constants (4 waves; each wave serves BOTH 16-row halves) ----
  const int l = tid & 63;
  const int nc = tid >> 6;           // wave 0..3
  const int nc0 = nc * 32;           // layers 2-4 col base (DF=128)
  const int arl = l & 15;            // A row within half
  const int kb = (l >> 4) * 8;
  const int drow = (l >> 4) * 4;
  const size_t fbase = (size_t)(2 * nc) * 512 + (size_t)l * 8;

  // tile types per 16-row half
  int ty0 = 0, ty1 = 0;
#pragma unroll
  for (int t2 = 1; t2 < N_AA; ++t2) {
    if (base >= s_off[t2]) ty0 = t2;
    if (base + 16 >= s_off[t2]) ty1 = t2;
  }

  // ---- layer 1: h1 = relu(feat96 @ W1type + tabAA + tabCH) ----
  {
    f32x4 acc0[4] = {{0.f,0.f,0.f,0.f},{0.f,0.f,0.f,0.f},{0.f,0.f,0.f,0.f},{0.f,0.f,0.f,0.f}};
    f32x4 acc1[4] = {{0.f,0.f,0.f,0.f},{0.f,0.f,0.f,0.f},{0.f,0.f,0.f,0.f},{0.f,0.f,0.f,0.f}};
    const unsigned short* pB0 = wl1 + ((size_t)ty0 * 48 + 4 * nc) * 512 + (size_t)l * 8;
    const unsigned short* pB1 = wl1 + ((size_t)ty1 * 48 + 4 * nc) * 512 + (size_t)l * 8;
#pragma unroll
    for (int c = 0; c < 3; ++c) {
      const s16x8 ah0 = *(const s16x8*)(&s_fh[arl][c * 32 + kb]);
      const s16x8 ah1 = *(const s16x8*)(&s_fh[16 + arl][c * 32 + kb]);
#pragma unroll
      for (int nt2 = 0; nt2 < 4; ++nt2) {
        const s16x8 bb0 = *(const s16x8*)(pB0 + ((size_t)c * 16 + nt2) * 512);
        acc0[nt2] = __builtin_amdgcn_mfma_f32_16x16x32_bf16(ah0, bb0, acc0[nt2], 0, 0, 0);
        const s16x8 bb1 = (ty1 == ty0) ? bb0
            : *(const s16x8*)(pB1 + ((size_t)c * 16 + nt2) * 512);
        acc1[nt2] = __builtin_amdgcn_mfma_f32_16x16x32_bf16(ah1, bb1, acc1[nt2], 0, 0, 0);
      }
    }
    __syncthreads();  // all feature reads done (h2 later overwrites s_u)
#pragma unroll
    for (int nt2 = 0; nt2 < 4; ++nt2) {
      const int col0 = nc * 64 + nt2 * 16 + (l & 15);
      const float ta0 = tabAA[ty0 * H1DIM + col0];
      const float ta1 = tabAA[ty1 * H1DIM + col0];
#pragma unroll
      for (int reg = 0; reg < 4; ++reg) {
        const int row0 = drow + reg;
        float v0 = acc0[nt2][reg] + ta0 + tabCH[s_c[row0] * H1DIM + col0];
        s_h1hi[row0][col0] = f2bf(fmaxf(v0, 0.f));
        const int row1 = 16 + drow + reg;
        float v1 = acc1[nt2][reg] + ta1 + tabCH[s_c[row1] * H1DIM + col0];
        s_h1hi[row1][col0] = f2bf(fmaxf(v1, 0.f));
      }
    }
  }
  __syncthreads();  // h1 visible

// Two row-halves share every B-frag load (halves weight L2 traffic).
#define MFMA_LAYER(NCHUNK, CG0, SRCH, SSTR, BPTR, EPI)                           \
  do {                                                                           \
    f32x4 a0c0 = {0.f,0.f,0.f,0.f}, a0c1 = {0.f,0.f,0.f,0.f};                    \
    f32x4 a1c0 = {0.f,0.f,0.f,0.f}, a1c1 = {0.f,0.f,0.f,0.f};                    \
    const unsigned short* ph = wf_hi + (size_t)(CG0)*4096 + fbase;               \
    const unsigned short* pl = wf_lo + (size_t)(CG0)*4096 + fbase;               \
    _Pragma("unroll 2")                                                          \
    for (int c = 0; c < (NCHUNK); ++c) {                                         \
      const s16x8 b0h = *(const s16x8*)(ph + (size_t)c * 4096);                  \
      const s16x8 b1h = *(const s16x8*)(ph + (size_t)c * 4096 + 512);            \
      const s16x8 b0l = *(const s16x8*)(pl + (size_t)c * 4096);                  \
      const s16x8 b1l = *(const s16x8*)(pl + (size_t)c * 4096 + 512);            \
      const int ko = c * 32 + kb;                                                \
      const s16x8 ah0 = *(const s16x8*)((SRCH) + arl * (SSTR) + ko);             \
      const s16x8 ah1 = *(const s16x8*)((SRCH) + (16 + arl) * (SSTR) + ko);      \
      a0c0 = __builtin_amdgcn_mfma_f32_16x16x32_bf16(ah0, b0h, a0c0, 0, 0, 0);   \
      a0c1 = __builtin_amdgcn_mfma_f32_16x16x32_bf16(ah0, b1h, a0c1, 0, 0, 0);   \
      a1c0 = __builtin_amdgcn_mfma_f32_16x16x32_bf16(ah1, b0h, a1c0, 0, 0, 0);   \
      a1c1 = __builtin_amdgcn_mfma_f32_16x16x32_bf16(ah1, b1h, a1c1, 0, 0, 0);   \
      a0c0 = __builtin_amdgcn_mfma_f32_16x16x32_bf16(ah0, b0l, a0c0, 0, 0, 0);   \
      a0c1 = __builtin_amdgcn_mfma_f32_16x16x32_bf16(ah0, b1l, a0c1, 0, 0, 0);   \
      a1c0 = __builtin_amdgcn_mfma_f32_16x16x32_bf16(ah1, b0l, a1c0, 0, 0, 0);   \
      a1c1 = __builtin_amdgcn_mfma_f32_16x16x32_bf16(ah1, b1l, a1c1, 0, 0, 0);   \
    }                                                                            \
    const float bias0 = (BPTR)[nc0 + (l & 15)];                                  \
    const float bias1 = (BPTR)[nc0 + 16 + (l & 15)];                             \
    EPI                                                                          \
  } while (0)

#define EPI_HIDDEN(DH, DSTR)                                                     \
  {                                                                              \
    _Pragma("unroll")                                                            \
    for (int reg = 0; reg < 4; ++reg) {                                          \
      const int row0 = drow + reg, row1 = 16 + drow + reg;                       \
      (DH)[row0 * (DSTR) + nc0 + (l & 15)] = f2bf(fmaxf(a0c0[reg] + bias0, 0.f));\
      (DH)[row0 * (DSTR) + nc0 + 16 + (l & 15)] = f2bf(fmaxf(a0c1[reg] + bias1, 0.f));\
      (DH)[row1 * (DSTR) + nc0 + (l & 15)] = f2bf(fmaxf(a1c0[reg] + bias0, 0.f));\
      (DH)[row1 * (DSTR) + nc0 + 16 + (l & 15)] = f2bf(fmaxf(a1c1[reg] + bias1, 0.f));\
    }                                                                            \
  }

  // ---- layer 2: K=256 (h2 overwrites feature region of s_u) ----
  MFMA_LAYER(8, 0, &s_h1hi[0][0], HS1, b2, EPI_HIDDEN(&s_h2hi[0][0], HS2));
  __syncthreads();

  // ---- layer 3: K=128 -> overwrite s_h1 ----
  MFMA_LAYER(4, 8, &s_h2hi[0][0], HS2, b3, EPI_HIDDEN(&s_h1hi[0][0], HS1));
  __syncthreads();

  // ---- layer 4: K=128, scatter-store via perm ----
  MFMA_LAYER(4, 12, &s_h1hi[0][0], HS1, b4, {
    _Pragma("unroll")
    for (int reg = 0; reg < 4; ++reg) {
      const unsigned int g0 = s_g[drow + reg];
      if (g0 != INVALID_IDX) {
        out[(size_t)g0 * DF + nc0 + (l & 15)] = a0c0[reg] + bias0;
        out[(size_t)g0 * DF + nc0 + 16 + (l & 15)] = a0c1[reg] + bias1;
      }
      const unsigned int g1 = s_g[16 + drow + reg];
      if (g1 != INVALID_IDX) {
        out[(size_t)g1 * DF + nc0 + (l & 15)] = a1c0[reg] + bias0;
        out[(size_t)g1 * DF + nc0 + 16 + (l & 15)] = a1c1[reg] + bias1;
      }
    }
  });
}

// ---------------- fp32 fallback path kernels ----------------
__global__ __launch_bounds__(256) void precompute_tables(
    const float* __restrict__ aa_emb, const float* __restrict__ chain_emb,
    const float* __restrict__ W1, const float* __restrict__ b1,
    float* __restrict__ tabAA, float* __restrict__ tabCH) {
  const int i = threadIdx.x;
  const int b = blockIdx.x;
  if (b < N_AA) {
    const float* e = aa_emb + b * DF;
    float acc = 0.f;
#pragma unroll 8
    for (int k = 0; k < DF; ++k) acc = fmaf(e[k], W1[k * H1DIM + i], acc);
    tabAA[b * H1DIM + i] = acc;
  } else {
    const int c = b - N_AA;
    const float* e = chain_emb + c * DF;
    float acc = b1[i];
#pragma unroll 8
    for (int k = 0; k < DF; ++k)
      acc = fmaf(e[k], W1[(OFF_CHAIN + k) * H1DIM + i], acc);
    tabCH[c * H1DIM + i] = acc;
  }
}

__global__ __launch_bounds__(512, 4) void residue_embed_fallback(
    const int* __restrict__ seq_idx, const float* __restrict__ xyz,
    const float* __restrict__ orient, const float* __restrict__ dihedrals,
    const int* __restrict__ chain_idx, const float* __restrict__ amask,
    const float* __restrict__ W1, const float* __restrict__ W2,
    const float* __restrict__ b2, const float* __restrict__ W3,
    const float* __restrict__ b3, const float* __restrict__ W4,
    const float* __restrict__ b4, const float* __restrict__ tabAA,
    const float* __restrict__ tabCH, float* __restrict__ out) {
  __shared__ float s_h1[FT][260];
  __shared__ float s_buf2[FT][132];
  __shared__ float s_w[32 * DF];
  __shared__ int s_t[FT];
  __shared__ int s_c[FT];

  const int tid = threadIdx.x;
  const int base = blockIdx.x * FT;

  if (tid < FT) {
    s_t[tid] = seq_idx[base + tid];
    s_c[tid] = chain_idx[base + tid];
  }
  for (int idx = tid; idx < FT * 45; idx += 512) {
    const int r = idx / 45, k = idx % 45;
    const int a = k / 3, i = k % 3;
    const int g = base + r;
    const float* X = xyz + g * 45;
    const float* R = orient + g * 9;
    const float m = amask[g * NATOM + a];
    float v = 0.f;
#pragma unroll
    for (int j = 0; j < 3; ++j)
      v = fmaf(R[j * 3 + i], X[a * 3 + j] - X[3 + j], v);
    s_buf2[r][k] = v * m;
  }
  for (int idx = tid; idx < FT * 39; idx += 512) {
    const int r = idx / 39, k = idx % 39;
    const int d = k / 13, m = k % 13;
    const float x = dihedrals[(base + r) * 3 + d];
    float v;
    if (m == 0) v = x;
    else if (m <= 6) v = sinf(c_freq[m - 1] * x);
    else v = cosf(c_freq[m - 7] * x);
    s_buf2[r][DIH0 + k] = v;
  }
  __syncthreads();
  {
    const int i0 = (tid & 63) * 4;
    const int r0 = (tid >> 6) * 4;
    float4 acc[4];
#pragma unroll
    for (int rr = 0; rr < 4; ++rr) {
      const int t = s_t[r0 + rr], c = s_c[r0 + rr];
      const float4 a = *(const float4*)(tabAA + t * H1DIM + i0);
      const float4 b = *(const float4*)(tabCH + c * H1DIM + i0);
      acc[rr].x = a.x + b.x; acc[rr].y = a.y + b.y;
      acc[rr].z = a.z + b.z; acc[rr].w = a.w + b.w;
    }
#pragma unroll 3
    for (int k = 0; k < 39; ++k) {
      const float4 wv = *(const float4*)(W1 + (OFF_DIH + k) * H1DIM + i0);
#pragma unroll
      for (int rr = 0; rr < 4; ++rr) {
        FMA4(acc[rr], s_buf2[r0 + rr][DIH0 + k], wv);
      }
    }
    const float* wp[4];
#pragma unroll
    for (int rr = 0; rr < 4; ++rr)
      wp[rr] = W1 + (OFF_COORD + s_t[r0 + rr] * 45) * H1DIM + i0;
    for (int k = 0; k < 45; ++k) {
#pragma unroll
      for (int rr = 0; rr < 4; ++rr) {
        const float4 wv = *(const float4*)(wp[rr] + k * H1DIM);
        FMA4(acc[rr], s_buf2[r0 + rr][k], wv);
      }
    }
#pragma unroll
    for (int rr = 0; rr < 4; ++rr) {
      float4 v;
      v.x = fmaxf(acc[rr].x, 0.f); v.y = fmaxf(acc[rr].y, 0.f);
      v.z = fmaxf(acc[rr].z, 0.f); v.w = fmaxf(acc[rr].w, 0.f);
      *(float4*)(&s_h1[r0 + rr][i0]) = v;
    }
  }
  const int j0 = (tid & 31) * 4;
  const int r2 = (tid >> 5) * 2;
#define FB_LAYER(NCH, WSRC, SRC, BPTR, STORE)                               \
  do {                                                                      \
    const float4 bb = *(const float4*)((BPTR) + j0);                        \
    float4 acc0 = bb, acc1 = bb;                                            \
    for (int c = 0; c < (NCH); ++c) {                                       \
      __syncthreads();                                                      \
      {                                                                     \
        const float* src = (WSRC) + c * 32 * DF;                            \
        const int idx = tid * 8;                                            \
        *(float4*)(&s_w[idx]) = *(const float4*)(src + idx);                \
        *(float4*)(&s_w[idx + 4]) = *(const float4*)(src + idx + 4);        \
      }                                                                     \
      __syncthreads();                                                      \
      const int kb2 = c * 32;                                               \
      _Pragma("unroll")                                                     \
      for (int kk = 0; kk < 32; kk += 4) {                                  \
        const float4 a0 = *(const float4*)(&(SRC)[r2][kb2 + kk]);           \
        const float4 a1 = *(const float4*)(&(SRC)[r2 + 1][kb2 + kk]);       \
        const float4 w0 = *(const float4*)(&s_w[(kk + 0) * DF + j0]);       \
        const float4 w1 = *(const float4*)(&s_w[(kk + 1) * DF + j0]);       \
        const float4 w2 = *(const float4*)(&s_w[(kk + 2) * DF + j0]);       \
        const float4 w3 = *(const float4*)(&s_w[(kk + 3) * DF + j0]);       \
        FMA4(acc0, a0.x, w0); FMA4(acc1, a1.x, w0);                         \
        FMA4(acc0, a0.y, w1); FMA4(acc1, a1.y, w1);                         \
        FMA4(acc0, a0.z, w2); FMA4(acc1, a1.z, w2);                         \
        FMA4(acc0, a0.w, w3); FMA4(acc1, a1.w, w3);                         \
      }                                                                     \
    }                                                                       \
    STORE                                                                   \
  } while (0)
#define RELU_STORE(DST)                                                     \
  {                                                                         \
    float4 v0, v1;                                                          \
    v0.x = fmaxf(acc0.x, 0.f); v0.y = fmaxf(acc0.y, 0.f);                   \
    v0.z = fmaxf(acc0.z, 0.f); v0.w = fmaxf(acc0.w, 0.f);                   \
    v1.x = fmaxf(acc1.x, 0.f); v1.y = fmaxf(acc1.y, 0.f);                   \
    v1.z = fmaxf(acc1.z, 0.f); v1.w = fmaxf(acc1.w, 0.f);                   \
    *(float4*)(&(DST)[r2][j0]) = v0;                                        \
    *(float4*)(&(DST)[r2 + 1][j0]) = v1;                                    \
  }
  FB_LAYER(8, W2, s_h1, b2, RELU_STORE(s_buf2));
  FB_LAYER(4, W3, s_buf2, b3, RELU_STORE(s_h1));
  FB_LAYER(4, W4, s_h1, b4, {
    *(float4*)(out + (size_t)(base + r2) * DF + j0) = acc0;
    *(float4*)(out + (size_t)(base + r2 + 1) * DF + j0) = acc1;
  });
}

extern "C" void kernel_launch(void* const* d_in, const int* in_sizes, int n_in,
                              void* d_out, int out_size, void* d_ws, size_t ws_size,
                              hipStream_t stream) {
  const int* seq = (const int*)d_in[0];
  const float* xyz = (const float*)d_in[1];
  const float* orient = (const float*)d_in[2];
  const float* dihedrals = (const float*)d_in[3];
  const int* chain = (const int*)d_in[4];
  const float* amask = (const float*)d_in[5];
  const float* aa_emb = (const float*)d_in[6];
  const float* chain_emb = (const float*)d_in[7];
  const float* W1 = (const float*)d_in[8];
  const float* b1 = (const float*)d_in[9];
  const float* W2 = (const float*)d_in[10];
  const float* b2 = (const float*)d_in[11];
  const float* W3 = (const float*)d_in[12];
  const float* b3 = (const float*)d_in[13];
  const float* W4 = (const float*)d_in[14];
  const float* b4 = (const float*)d_in[15];
  float* out = (float*)d_out;
  const int n_res = in_sizes[0];  // B*L = 32768

  const int nblkH = (n_res + 255) / 256;

  // ---- ws layout ----
  char* wsp = (char*)d_ws;
  const size_t o_tabAA = 0;
  const size_t o_tabCH = o_tabAA + (size_t)N_AA * H1DIM * 4;
  const size_t o_wfhi = (o_tabCH + (size_t)10 * H1DIM * 4 + 255) & ~255ull;
  const size_t o_wflo = o_wfhi + (size_t)NFRAG_CH * 8 * 512 * 2;
  const size_t o_wl1 = o_wflo + (size_t)NFRAG_CH * 8 * 512 * 2;
  const size_t wl1_bytes = (size_t)N_AA * 3 * 16 * 512 * 2;
  const size_t o_part = (o_wl1 + wl1_bytes + 255) & ~255ull;   // nblkH*21 ints
  const size_t o_tot = (o_part + (size_t)nblkH * N_AA * 4 + 255) & ~255ull;
  const size_t o_perm = (o_tot + N_AA * 4 + 255) & ~255ull;
  const int npad_max = n_res + N_AA * 15;
  const int nblkB = (npad_max + T - 1) / T;
  const int cap = nblkB * T;
  const size_t perm_bytes = (size_t)cap * 4;
  const size_t need = o_perm + perm_bytes;

  float* tabAA = (float*)(wsp + o_tabAA);
  float* tabCH = (float*)(wsp + o_tabCH);

  if (ws_size >= need) {
    unsigned short* wf_hi = (unsigned short*)(wsp + o_wfhi);
    unsigned short* wf_lo = (unsigned short*)(wsp + o_wflo);
    unsigned short* wl1 = (unsigned short*)(wsp + o_wl1);
    int* part = (int*)(wsp + o_part);
    int* totals = (int*)(wsp + o_tot);
    unsigned int* perm = (unsigned int*)(wsp + o_perm);

    hipLaunchKernelGGL(hist_part, dim3(nblkH), dim3(256), 0, stream, seq,
                       n_res, part);

    hipLaunchKernelGGL(prep_scatter, dim3(PR_NW + nblkH + N_AA + 1), dim3(256),
                       0, stream, aa_emb, chain_emb, W1, b1, W2, W3, W4, seq,
                       n_res, tabAA, tabCH, wf_hi, wf_lo, wl1, part, cap,
                       nblkH, totals, perm);

    hipLaunchKernelGGL(residue_embed_sorted, dim3(nblkB), dim3(256), 0, stream,
                       xyz, orient, dihedrals, chain, amask, b2, b3, b4, tabAA,
                       tabCH, wl1, wf_hi, wf_lo, totals, perm, out);
  } else {
    hipLaunchKernelGGL(precompute_tables, dim3(N_AA + 10), dim3(256), 0, stream,
                       aa_emb, chain_emb, W1, b1, tabAA, tabCH);
    const int nblk = n_res / FT;
    hipLaunchKernelGGL(residue_embed_fallback, dim3(nblk), dim3(512), 0, stream,
                       seq, xyz, orient, dihedrals, chain, amask, W1, W2, b2,
                       W3, b3, W4, b4, tabAA, tabCH, out);
  }
}